// Round 1
// baseline (334.399 us; speedup 1.0000x reference)
//
#include <hip/hip_runtime.h>
#include <cmath>

#define TPB   128
#define CHUNK 64
#define DIM   64
#define MCODE 512
#define ROWS  131072
#define QELEMS 8388608   // 32*4096*64

// ---------------- prep: c[m] = ||e_m||^2 (numpy pairwise order), zero accumulators
__global__ __launch_bounds__(512) void vq_prep(const float* __restrict__ E,
                                               float* __restrict__ cvec,
                                               unsigned int* __restrict__ counts,
                                               double* __restrict__ lsum) {
    const int m = threadIdx.x;            // 512 threads, 1 block
    counts[m] = 0u;
    if (m == 0) *lsum = 0.0;
    const float* e = E + (size_t)m * DIM;
    // numpy pairwise_sum for n=64: 8 accumulators stride 8, then tree combine
    float r[8];
#pragma unroll
    for (int j = 0; j < 8; ++j) r[j] = e[j] * e[j];
#pragma unroll
    for (int i = 1; i < 8; ++i)
#pragma unroll
        for (int j = 0; j < 8; ++j) r[j] += e[8 * i + j] * e[8 * i + j];
    cvec[m] = ((r[0] + r[1]) + (r[2] + r[3])) + ((r[4] + r[5]) + (r[6] + r[7]));
}

// ---------------- main: argmin over codes, write quantised_st, loss + histogram
__global__ __launch_bounds__(TPB) void vq_main(const float* __restrict__ X,
                                               const float* __restrict__ E,
                                               const float* __restrict__ cvec,
                                               float* __restrict__ out,
                                               unsigned int* __restrict__ counts,
                                               double* __restrict__ lsum) {
    __shared__ __align__(16) float sE[CHUNK * DIM];   // 16 KB
    __shared__ float sc[CHUNK];
    __shared__ unsigned int hist[MCODE];              // 2 KB
    __shared__ double red[TPB / 64];

    const int tid = threadIdx.x;
    for (int i = tid; i < MCODE; i += TPB) hist[i] = 0u;

    const size_t row = (size_t)blockIdx.x * TPB + tid;
    const float* xp = X + row * DIM;
    float x[DIM];
#pragma unroll
    for (int i = 0; i < DIM / 4; ++i) {
        const float4 v = reinterpret_cast<const float4*>(xp)[i];
        x[4 * i + 0] = v.x; x[4 * i + 1] = v.y;
        x[4 * i + 2] = v.z; x[4 * i + 3] = v.w;
    }

    // ||x||^2 in numpy pairwise order (elementwise square first, then 8-acc sum)
    float r[8];
#pragma unroll
    for (int j = 0; j < 8; ++j) r[j] = x[j] * x[j];
#pragma unroll
    for (int i = 1; i < 8; ++i)
#pragma unroll
        for (int j = 0; j < 8; ++j) r[j] += x[8 * i + j] * x[8 * i + j];
    const float nx = ((r[0] + r[1]) + (r[2] + r[3])) + ((r[4] + r[5]) + (r[6] + r[7]));

    float best = __builtin_inff();
    int bidx = 0;

    for (int ch = 0; ch < MCODE / CHUNK; ++ch) {
        __syncthreads();   // protect LDS buffer reuse (also orders hist zeroing)
        // stage CHUNK codes (coalesced): 1024 float4 / 128 threads = 8 each
        const float4* src = reinterpret_cast<const float4*>(E + (size_t)ch * CHUNK * DIM);
        float4* dst = reinterpret_cast<float4*>(sE);
#pragma unroll
        for (int i = 0; i < (CHUNK * DIM / 4) / TPB; ++i)
            dst[i * TPB + tid] = src[i * TPB + tid];
        if (tid < CHUNK) sc[tid] = cvec[ch * CHUNK + tid];
        __syncthreads();

#pragma unroll 2
        for (int mm = 0; mm < CHUNK; ++mm) {
            const float* e = sE + mm * DIM;   // broadcast reads, conflict-free
            float d = 0.f;
#pragma unroll
            for (int k = 0; k < DIM; ++k) d = fmaf(x[k], e[k], d);   // sequential K, BLAS-like
            // (nx - 2*d) in ONE rounding (2*d exact), then + c[m] in one rounding:
            // identical op structure to numpy's  ||x||^2 - 2*(x@E^T) + ||e||^2
            const float d2 = fmaf(-2.f, d, nx) + sc[mm];
            const int m = ch * CHUNK + mm;
            if (d2 < best) { best = d2; bidx = m; }   // strict <  => first-min, np.argmin
        }
    }

    atomicAdd(&hist[bidx], 1u);

    // quantised_st = x + (q - x)  (mimic reference arithmetic), loss = (x - q)^2
    const float* q = E + (size_t)bidx * DIM;   // divergent, but L2-resident (128 KB)
    float4* op = reinterpret_cast<float4*>(out + row * DIM);
    float ls = 0.f;
#pragma unroll
    for (int i = 0; i < DIM / 4; ++i) {
        const float4 qv = reinterpret_cast<const float4*>(q)[i];
        float4 o;
        {   float xx = x[4 * i + 0]; float t = qv.x - xx; o.x = xx + t;
            float dd = xx - qv.x; ls = fmaf(dd, dd, ls); }
        {   float xx = x[4 * i + 1]; float t = qv.y - xx; o.y = xx + t;
            float dd = xx - qv.y; ls = fmaf(dd, dd, ls); }
        {   float xx = x[4 * i + 2]; float t = qv.z - xx; o.z = xx + t;
            float dd = xx - qv.z; ls = fmaf(dd, dd, ls); }
        {   float xx = x[4 * i + 3]; float t = qv.w - xx; o.w = xx + t;
            float dd = xx - qv.w; ls = fmaf(dd, dd, ls); }
        op[i] = o;
    }

    // block loss reduction -> one double atomic per block
#pragma unroll
    for (int off = 32; off > 0; off >>= 1) ls += __shfl_down(ls, off);
    const int lane = tid & 63, wid = tid >> 6;
    if (lane == 0) red[wid] = (double)ls;
    __syncthreads();                     // also orders hist atomics before flush
    if (tid == 0) {
        double s = 0.0;
#pragma unroll
        for (int w = 0; w < TPB / 64; ++w) s += red[w];
        atomicAdd(lsum, s);
    }
    for (int i = tid; i < MCODE; i += TPB) {
        const unsigned v = hist[i];
        if (v) atomicAdd(&counts[i], v);
    }
}

// ---------------- finalize: losses + perplexity
__global__ __launch_bounds__(512) void vq_fin(const unsigned int* __restrict__ counts,
                                              const double* __restrict__ lsum,
                                              float* __restrict__ out3) {
    __shared__ double sred[8];
    const int t = threadIdx.x;           // 512 threads, 1 block
    const double avg = (double)counts[t] / (double)ROWS;
    double term = avg * log(avg + 1e-10);
#pragma unroll
    for (int off = 32; off > 0; off >>= 1) term += __shfl_down(term, off);
    const int lane = t & 63, wid = t >> 6;
    if (lane == 0) sred[wid] = term;
    __syncthreads();
    if (t == 0) {
        double s = 0.0;
#pragma unroll
        for (int w = 0; w < 8; ++w) s += sred[w];
        const float perp = (float)exp(-s);
        const float rl = (float)(*lsum / (double)QELEMS);
        out3[0] = 0.25f * rl;   // commitment_loss
        out3[1] = rl;           // codebook_loss
        out3[2] = perp;         // perplexity
    }
}

extern "C" void kernel_launch(void* const* d_in, const int* in_sizes, int n_in,
                              void* d_out, int out_size, void* d_ws, size_t ws_size,
                              hipStream_t stream) {
    const float* X = (const float*)d_in[0];       // [32,4096,64] fp32
    const float* E = (const float*)d_in[1];       // [512,64] fp32
    float* out = (float*)d_out;                   // 8388608 + 3 floats

    double* lsum = (double*)d_ws;
    unsigned int* counts = (unsigned int*)((char*)d_ws + 8);
    float* cvec = (float*)((char*)d_ws + 8 + MCODE * sizeof(unsigned int));

    vq_prep<<<1, MCODE, 0, stream>>>(E, cvec, counts, lsum);
    vq_main<<<ROWS / TPB, TPB, 0, stream>>>(X, E, cvec, out, counts, lsum);
    vq_fin<<<1, MCODE, 0, stream>>>(counts, lsum, out + QELEMS);
}

// Round 2
// 135.805 us; speedup vs baseline: 2.4624x; 2.4624x over previous
//
#include <hip/hip_runtime.h>
#include <cmath>

#define DIM    64
#define MCODE  512
#define ROWS   131072
#define QELEMS 8388608   // 32*4096*64
#define BM     128       // rows per block
#define BCODE  128       // codes per chunk
#define NCHUNK 4
#define TPB    256
#define LDF    132       // padded floats per k-plane
#define LDK    33        // float4 per k-plane

// ---------------- prep: c[m] = ||e_m||^2 (numpy pairwise order), zero accumulators
__global__ __launch_bounds__(512) void vq_prep(const float* __restrict__ E,
                                               float* __restrict__ cvec,
                                               unsigned int* __restrict__ counts,
                                               double* __restrict__ lsum) {
    const int m = threadIdx.x;            // 512 threads, 1 block
    counts[m] = 0u;
    if (m == 0) *lsum = 0.0;
    const float* e = E + (size_t)m * DIM;
    float r[8];
#pragma unroll
    for (int j = 0; j < 8; ++j) r[j] = e[j] * e[j];
#pragma unroll
    for (int i = 1; i < 8; ++i)
#pragma unroll
        for (int j = 0; j < 8; ++j) r[j] += e[8 * i + j] * e[8 * i + j];
    cvec[m] = ((r[0] + r[1]) + (r[2] + r[3])) + ((r[4] + r[5]) + (r[6] + r[7]));
}

// ---------------- main: register-tiled distance GEMM + argmin + outputs
__global__ __launch_bounds__(TPB, 2) void vq_main(const float* __restrict__ X,
                                                  const float* __restrict__ E,
                                                  const float* __restrict__ cvec,
                                                  float* __restrict__ out,
                                                  unsigned int* __restrict__ counts,
                                                  double* __restrict__ lsum) {
    __shared__ __align__(16) float4 xT4[64 * LDK];   // 33792 B, x transposed [k][row]
    __shared__ __align__(16) float4 eT4[64 * LDK];   // 33792 B, e transposed [k][code]
    __shared__ float nxs[BM];
    __shared__ float sc[BCODE];
    __shared__ int bidxs[BM];
    __shared__ unsigned int hist[MCODE];
    __shared__ double red[TPB / 64];

    const int tid = threadIdx.x;
    const int rg = tid >> 4;    // 0..15 row group
    const int cg = tid & 15;    // 0..15 code group
    float* xT = reinterpret_cast<float*>(xT4);
    float* eT = reinterpret_cast<float*>(eT4);

    for (int i = tid; i < MCODE; i += TPB) hist[i] = 0u;

    // ---- stage X block transposed: xT[k][row]
    const float* Xb = X + (size_t)blockIdx.x * BM * DIM;
#pragma unroll
    for (int i = 0; i < 8; ++i) {
        const int g = i * TPB + tid;                 // float4 index, coalesced
        const float4 v = reinterpret_cast<const float4*>(Xb)[g];
        const int row = g >> 4;
        const int k0 = 4 * (tid & 15);
        xT[(k0 + 0) * LDF + row] = v.x;
        xT[(k0 + 1) * LDF + row] = v.y;
        xT[(k0 + 2) * LDF + row] = v.z;
        xT[(k0 + 3) * LDF + row] = v.w;
    }
    __syncthreads();

    // ---- ||x||^2 per row, numpy pairwise 8-acc order
    if (tid < BM) {
        float r[8];
#pragma unroll
        for (int j = 0; j < 8; ++j) { const float t = xT[j * LDF + tid]; r[j] = t * t; }
#pragma unroll
        for (int i = 1; i < 8; ++i)
#pragma unroll
            for (int j = 0; j < 8; ++j) { const float t = xT[(8 * i + j) * LDF + tid]; r[j] += t * t; }
        nxs[tid] = ((r[0] + r[1]) + (r[2] + r[3])) + ((r[4] + r[5]) + (r[6] + r[7]));
    }
    __syncthreads();

    float nx[8];
#pragma unroll
    for (int xi = 0; xi < 8; ++xi) {
        const int row = (xi < 4) ? (4 * rg + xi) : (64 + 4 * rg + xi - 4);
        nx[xi] = nxs[row];
    }

    float bd[8]; int bi[8];
#pragma unroll
    for (int xi = 0; xi < 8; ++xi) { bd[xi] = __builtin_inff(); bi[xi] = 0; }

    for (int ch = 0; ch < NCHUNK; ++ch) {
        __syncthreads();   // previous chunk's reads done before overwrite
        // ---- stage E chunk transposed: eT[k][code]
        const float* Eb = E + (size_t)ch * BCODE * DIM;
#pragma unroll
        for (int i = 0; i < 8; ++i) {
            const int g = i * TPB + tid;
            const float4 v = reinterpret_cast<const float4*>(Eb)[g];
            const int code = g >> 4;
            const int k0 = 4 * (tid & 15);
            eT[(k0 + 0) * LDF + code] = v.x;
            eT[(k0 + 1) * LDF + code] = v.y;
            eT[(k0 + 2) * LDF + code] = v.z;
            eT[(k0 + 3) * LDF + code] = v.w;
        }
        if (tid < BCODE) sc[tid] = cvec[ch * BCODE + tid];
        __syncthreads();

        float acc[8][8];
#pragma unroll
        for (int xi = 0; xi < 8; ++xi)
#pragma unroll
            for (int ei = 0; ei < 8; ++ei) acc[xi][ei] = 0.f;

#pragma unroll 2
        for (int k = 0; k < DIM; ++k) {
            const float4 xlo = xT4[k * LDK + rg];        // rows 4rg..4rg+3   (broadcast x16)
            const float4 xhi = xT4[k * LDK + 16 + rg];   // rows 64+4rg..
            const float4 elo = eT4[k * LDK + cg];        // codes 4cg..4cg+3
            const float4 ehi = eT4[k * LDK + 16 + cg];   // codes 64+4cg..
            const float xa[8] = {xlo.x, xlo.y, xlo.z, xlo.w, xhi.x, xhi.y, xhi.z, xhi.w};
            const float ea[8] = {elo.x, elo.y, elo.z, elo.w, ehi.x, ehi.y, ehi.z, ehi.w};
#pragma unroll
            for (int xi = 0; xi < 8; ++xi)
#pragma unroll
                for (int ei = 0; ei < 8; ++ei)
                    acc[xi][ei] = fmaf(xa[xi], ea[ei], acc[xi][ei]);  // sequential k, same as ref
        }

        // ---- combine + per-thread argmin (codes ascend with ei; strict <)
#pragma unroll
        for (int ei = 0; ei < 8; ++ei) {
            const int cl = (ei < 4) ? (4 * cg + ei) : (64 + 4 * cg + ei - 4);
            const float c = sc[cl];
            const int code = ch * BCODE + cl;
#pragma unroll
            for (int xi = 0; xi < 8; ++xi) {
                const float d2 = fmaf(-2.f, acc[xi][ei], nx[xi]) + c;  // exact ref rounding
                if (d2 < bd[xi]) { bd[xi] = d2; bi[xi] = code; }
            }
        }
    }

    // ---- argmin reduce across the 16 cg lanes (within wave), ties -> smaller index
#pragma unroll
    for (int off = 1; off < 16; off <<= 1) {
#pragma unroll
        for (int xi = 0; xi < 8; ++xi) {
            const float od = __shfl_xor(bd[xi], off, 64);
            const int oi = __shfl_xor(bi[xi], off, 64);
            if (od < bd[xi] || (od == bd[xi] && oi < bi[xi])) { bd[xi] = od; bi[xi] = oi; }
        }
    }
    if (cg == 0) {
#pragma unroll
        for (int xi = 0; xi < 8; ++xi) {
            const int row = (xi < 4) ? (4 * rg + xi) : (64 + 4 * rg + xi - 4);
            bidxs[row] = bi[xi];
            atomicAdd(&hist[bi[xi]], 1u);
        }
    }
    __syncthreads();

    // ---- epilogue: quantised_st + loss, coalesced float4 writes
    float* outb = out + (size_t)blockIdx.x * BM * DIM;
    float ls = 0.f;
#pragma unroll
    for (int i = 0; i < 8; ++i) {
        const int g = i * TPB + tid;
        const int row = g >> 4;
        const int k0 = 4 * (tid & 15);
        const int bq = bidxs[row];
        const float4 q = reinterpret_cast<const float4*>(E + (size_t)bq * DIM)[tid & 15];
        float xv[4];
#pragma unroll
        for (int j = 0; j < 4; ++j) xv[j] = xT[(k0 + j) * LDF + row];
        float4 o;
        { const float t = q.x - xv[0]; o.x = xv[0] + t; const float dd = xv[0] - q.x; ls = fmaf(dd, dd, ls); }
        { const float t = q.y - xv[1]; o.y = xv[1] + t; const float dd = xv[1] - q.y; ls = fmaf(dd, dd, ls); }
        { const float t = q.z - xv[2]; o.z = xv[2] + t; const float dd = xv[2] - q.z; ls = fmaf(dd, dd, ls); }
        { const float t = q.w - xv[3]; o.w = xv[3] + t; const float dd = xv[3] - q.w; ls = fmaf(dd, dd, ls); }
        reinterpret_cast<float4*>(outb)[g] = o;
    }

    // ---- block loss reduction -> one double atomic
#pragma unroll
    for (int off = 32; off > 0; off >>= 1) ls += __shfl_down(ls, off);
    const int lane = tid & 63, wid = tid >> 6;
    if (lane == 0) red[wid] = (double)ls;
    __syncthreads();
    if (tid == 0) {
        double s = 0.0;
#pragma unroll
        for (int w = 0; w < TPB / 64; ++w) s += red[w];
        atomicAdd(lsum, s);
    }
    for (int i = tid; i < MCODE; i += TPB) {
        const unsigned int v = hist[i];
        if (v) atomicAdd(&counts[i], v);
    }
}

// ---------------- finalize: losses + perplexity
__global__ __launch_bounds__(512) void vq_fin(const unsigned int* __restrict__ counts,
                                              const double* __restrict__ lsum,
                                              float* __restrict__ out3) {
    __shared__ double sred[8];
    const int t = threadIdx.x;
    const double avg = (double)counts[t] / (double)ROWS;
    double term = avg * log(avg + 1e-10);
#pragma unroll
    for (int off = 32; off > 0; off >>= 1) term += __shfl_down(term, off);
    const int lane = t & 63, wid = t >> 6;
    if (lane == 0) sred[wid] = term;
    __syncthreads();
    if (t == 0) {
        double s = 0.0;
#pragma unroll
        for (int w = 0; w < 8; ++w) s += sred[w];
        const float perp = (float)exp(-s);
        const float rl = (float)(*lsum / (double)QELEMS);
        out3[0] = 0.25f * rl;   // commitment_loss
        out3[1] = rl;           // codebook_loss
        out3[2] = perp;         // perplexity
    }
}

extern "C" void kernel_launch(void* const* d_in, const int* in_sizes, int n_in,
                              void* d_out, int out_size, void* d_ws, size_t ws_size,
                              hipStream_t stream) {
    const float* X = (const float*)d_in[0];       // [32,4096,64] fp32
    const float* E = (const float*)d_in[1];       // [512,64] fp32
    float* out = (float*)d_out;                   // 8388608 + 3 floats

    double* lsum = (double*)d_ws;
    unsigned int* counts = (unsigned int*)((char*)d_ws + 8);
    float* cvec = (float*)((char*)d_ws + 8 + MCODE * sizeof(unsigned int));

    vq_prep<<<1, MCODE, 0, stream>>>(E, cvec, counts, lsum);
    vq_main<<<ROWS / BM, TPB, 0, stream>>>(X, E, cvec, out, counts, lsum);
    vq_fin<<<1, MCODE, 0, stream>>>(counts, lsum, out + QELEMS);
}